// Round 7
// baseline (888.732 us; speedup 1.0000x reference)
//
#include <hip/hip_runtime.h>
#include <math.h>

#define VOCAB 32768
#define DD 512
#define NB 3
#define NF 3
#define SEQ 4
#define MAX_ENT_F 10.3972077083991790f

// ---- ws layout (floats; ws is 256 MiB, re-poisoned 0xAA each replay, so
// everything here is written before read within each launch) ----
#define WS_MEM    0        // [9][512] = 4608 (zeroed by k_init)
#define WS_WBUB   4616     // [9]
#define WS_NORMED 4640     // [9][512] = 4608 (16B aligned)
#define WS_SLOT   9248     // [4][32]: 0-2 wmeta, 3-5 logSf, 6-14 coeff, 15 logSt, 16 srho
#define WS_CNT    9376     // 32 ints (zeroed by k_init): [t*3+f]=kA, [12+t]=kB, [16+t]=kC
#define WS_G      9472     // [45] Gram
#define WS_WT     9536     // [256] token partials
#define WS_PART   9792     // [12][1024] born-moment partials
#define WS_BORN   22528    // [3][VOCAB] (16B aligned)
#define WS_STP    122880   // [9][8][512] states partials

// pair index tables for i<=j over 9 (45 pairs)
__device__ const unsigned char PI9[45] = {
  0,0,0,0,0,0,0,0,0, 1,1,1,1,1,1,1,1, 2,2,2,2,2,2,2, 3,3,3,3,3,3,
  4,4,4,4,4, 5,5,5,5, 6,6,6, 7,7, 8};
__device__ const unsigned char PJ9[45] = {
  0,1,2,3,4,5,6,7,8, 1,2,3,4,5,6,7,8, 2,3,4,5,6,7,8, 3,4,5,6,7,8,
  4,5,6,7,8, 5,6,7,8, 6,7,8, 7,8, 8};

__device__ __forceinline__ float blockReduceSum(float v, float* sh) {
  int lane = threadIdx.x & 63;
  int wid  = threadIdx.x >> 6;
#pragma unroll
  for (int off = 32; off; off >>= 1) v += __shfl_down(v, off, 64);
  __syncthreads();
  if (lane == 0) sh[wid] = v;
  __syncthreads();
  int nw = blockDim.x >> 6;
  float r = 0.0f;
  if ((int)threadIdx.x < nw) r = sh[threadIdx.x];
  if (wid == 0) {
#pragma unroll
    for (int off = 8; off; off >>= 1) r += __shfl_down(r, off, 64);
    if (lane == 0) sh[0] = r;
  }
  __syncthreads();
  return sh[0];
}

__global__ void k_init(float* __restrict__ ws) {
  int i = blockIdx.x * 256 + threadIdx.x;
  if (i < NF * NB * DD) ws[WS_MEM + i] = 0.0f;
  if (i < 32) ((int*)(ws + WS_CNT))[i] = 0;
}

// ---------------- kA: states partials + last-man equil; blocks>=72: o_tok(t-1)
__global__ __launch_bounds__(256) void kA(const int* __restrict__ tokens,
        const float* __restrict__ E, const float* __restrict__ Ws,
        const float* __restrict__ base_p, const float* __restrict__ sens_p,
        float* __restrict__ ws, float* __restrict__ o_tok_prev,
        const float* __restrict__ o_d_prev, int t) {
  const int tid = threadIdx.x;
  __shared__ float smean[DD];
  __shared__ float xin_loc[64];
  __shared__ float red[16];
  __shared__ float s_decay;
  __shared__ int s_last;
  __shared__ float seq[NB * DD];
  __shared__ float snrm[NB];
  __shared__ float sc[7];

  if (blockIdx.x >= 72) {
    // ---- write o_tok for step t-1 ----
    const float* slot = ws + WS_SLOT + (size_t)(t - 1) * 32;
    if (tid < 6) sc[tid] = slot[tid];          // 0-2 wmeta, 3-5 logSf
    if (tid == 6) sc[6] = slot[15];            // logSt
    __syncthreads();
    const int v = (blockIdx.x - 72) * 256 + tid;
    float C = sc[0] * sc[3] + sc[1] * sc[4] + sc[2] * sc[5] - sc[6];
    float s = sc[0] * logf(o_d_prev[v]) + sc[1] * logf(o_d_prev[VOCAB + v]) +
              sc[2] * logf(o_d_prev[2 * VOCAB + v]);
    o_tok_prev[v] = expf(s + C);
    return;
  }

  // ---- states GEMV partial: fn = b/8, dc = b%8 ----
  const int fn = blockIdx.x >> 3, dc = blockIdx.x & 7;
  const int f = fn / NB;
  const int d0 = dc * 64;
  float* mem = ws + WS_MEM;
  const float* x = E + (size_t)tokens[t] * DD;
  const float* m = mem + f * (NB * DD);
  for (int d = tid; d < DD; d += 256)
    smean[d] = (m[d] + m[DD + d] + m[2 * DD + d]) * (1.0f / 3.0f);
  __syncthreads();
  float pxm = 0.f, pxx = 0.f, pmm = 0.f;
  for (int d = tid; d < DD; d += 256) {
    float xv = x[d], mv = smean[d];
    pxm += xv * mv; pxx += xv * xv; pmm += mv * mv;
  }
  float sxm = blockReduceSum(pxm, red);
  float sxx = blockReduceSum(pxx, red);
  float smm = blockReduceSum(pmm, red);
  if (tid == 0) {
    float mem_norm = sqrtf(smm) + 1e-10f;
    float x_norm   = sqrtf(sxx) + 1e-10f;
    float novelty  = (mem_norm > 1e-8f) ? (1.0f - sxm / (x_norm * mem_norm)) : 1.0f;
    float sens = fabsf(sens_p[0]);
    float z = base_p[0] - sens * novelty;
    s_decay = 1.0f / (1.0f + expf(-z));
  }
  __syncthreads();
  if (tid < 64) xin_loc[tid] = x[d0 + tid] + s_decay * smean[d0 + tid];
  __syncthreads();
  const float* W = Ws + (size_t)fn * DD * DD + (size_t)d0 * DD;
  float acc0 = 0.f, acc1 = 0.f;
#pragma unroll 8
  for (int dd = 0; dd < 64; dd++) {
    float xv = xin_loc[dd];
    acc0 += xv * W[dd * DD + tid];
    acc1 += xv * W[dd * DD + tid + 256];
  }
  float* o = ws + WS_STP + (fn * 8 + dc) * DD;
  o[tid] = acc0;
  o[tid + 256] = acc1;

  // ---- last man of this foam's 24 blocks runs equil ----
  __threadfence();
  if (tid == 0) {
    int old = atomicAdd(((int*)(ws + WS_CNT)) + (t * 3 + f), 1);
    s_last = (old == 23);
  }
  __syncthreads();
  if (!s_last) return;
  __threadfence();

  for (int i = tid; i < NB * DD; i += 256) {
    int n = i >> 9, e = i & 511;
    const float* src = ws + WS_STP + ((f * NB + n) * 8) * DD + e;
    float acc = 0.f;
#pragma unroll
    for (int c = 0; c < 8; c++) acc += src[c * DD];
    seq[i] = acc;
  }
  __syncthreads();
  for (int e = tid; e < DD; e += 256) {
    float a = seq[e], b = seq[DD + e], c = seq[2 * DD + e];
#pragma unroll
    for (int it = 0; it < 3; it++) {
      float mn = (a + b + c) * (1.0f / 3.0f);
      a += 0.3f * (mn - a);
      b += 0.3f * (mn - b);
      c += 0.3f * (mn - c);
    }
    seq[e] = a; seq[DD + e] = b; seq[2 * DD + e] = c;
  }
  __syncthreads();
  for (int n = 0; n < NB; n++) {
    float p = 0.f;
    for (int e = tid; e < DD; e += 256) { float v = seq[n * DD + e]; p += v * v; }
    float ss = blockReduceSum(p, red);
    if (tid == 0) snrm[n] = sqrtf(ss);
  }
  __syncthreads();
  if (tid == 0) {
    float n0 = snrm[0], n1 = snrm[1], n2 = snrm[2];
    float mx = fmaxf(2.0f * n0, fmaxf(2.0f * n1, 2.0f * n2));
    float e0 = expf(2.0f * n0 - mx), e1 = expf(2.0f * n1 - mx), e2 = expf(2.0f * n2 - mx);
    float sd = e0 + e1 + e2;
    ws[WS_WBUB + f * NB + 0] = e0 / sd;
    ws[WS_WBUB + f * NB + 1] = e1 / sd;
    ws[WS_WBUB + f * NB + 2] = e2 / sd;
  }
  float dec = s_decay;
  for (int i = tid; i < NB * DD; i += 256) {
    int n = i >> 9;
    float sv = seq[i];
    ws[WS_NORMED + f * NB * DD + i] = sv / (snrm[n] + 1e-10f);
    float old = mem[f * NB * DD + i];
    mem[f * NB * DD + i] = dec * old + (1.0f - dec) * sv;
  }
}

// One Jacobi rotation on named scalars; HW rcp/rsq/sqrt keep the chain short.
#define ROT(APP,APQ,AQQ,P1,Q1,P2,Q2,P3,Q3,P4,Q4,P5,Q5,P6,Q6,P7,Q7) do {           \
    float apq_ = APQ;                                                               \
    float den_ = (fabsf(apq_) > 1e-25f) ? apq_ : 1e-25f;                            \
    float th_  = 0.5f * (AQQ - APP) * __builtin_amdgcn_rcpf(den_);                  \
    float mag_ = __builtin_amdgcn_rcpf(fabsf(th_) +                                 \
                   __builtin_amdgcn_sqrtf(th_ * th_ + 1.f));                        \
    float tt_  = copysignf(mag_, th_);                                              \
    float cc_  = __builtin_amdgcn_rsqf(tt_ * tt_ + 1.f);                            \
    float sn_  = tt_ * cc_;                                                         \
    APP -= tt_ * apq_;  AQQ += tt_ * apq_;  APQ = 0.0f;                             \
    float a_, b_;                                                                   \
    a_ = P1; b_ = Q1; P1 = cc_ * a_ - sn_ * b_; Q1 = sn_ * a_ + cc_ * b_;           \
    a_ = P2; b_ = Q2; P2 = cc_ * a_ - sn_ * b_; Q2 = sn_ * a_ + cc_ * b_;           \
    a_ = P3; b_ = Q3; P3 = cc_ * a_ - sn_ * b_; Q3 = sn_ * a_ + cc_ * b_;           \
    a_ = P4; b_ = Q4; P4 = cc_ * a_ - sn_ * b_; Q4 = sn_ * a_ + cc_ * b_;           \
    a_ = P5; b_ = Q5; P5 = cc_ * a_ - sn_ * b_; Q5 = sn_ * a_ + cc_ * b_;           \
    a_ = P6; b_ = Q6; P6 = cc_ * a_ - sn_ * b_; Q6 = sn_ * a_ + cc_ * b_;           \
    a_ = P7; b_ = Q7; P7 = cc_ * a_ - sn_ * b_; Q7 = sn_ * a_ + cc_ * b_;           \
  } while (0)

// ---------------- kB: born + moments + Gram; last-man does scalars + Jacobi
__global__ __launch_bounds__(256) void kB(const float4* __restrict__ E4,
        float* __restrict__ ws, const float* __restrict__ temp_p,
        float* __restrict__ o_w, float* __restrict__ o_sr, int t) {
  const int tid = threadIdx.x, lane = tid & 63, wave = tid >> 6;
  const float4* N4 = (const float4*)(ws + WS_NORMED);
  float* born = ws + WS_BORN;
  float4 nr0[9], nr1[9];
#pragma unroll
  for (int j = 0; j < 9; j++) {
    nr0[j] = N4[j * 128 + lane];
    nr1[j] = N4[j * 128 + 64 + lane];
  }
  __shared__ float w9[9];
  __shared__ float sb2[12][4];
  __shared__ float r12[12];
  __shared__ int s_last;
  if (tid < 9) w9[tid] = ws[WS_WBUB + tid];
  __syncthreads();
  float pu0 = 0.f, pu1 = 0.f, pu2 = 0.f;
  float pub0 = 0.f, pub1 = 0.f, pub2 = 0.f;
  float puu0 = 0.f, puu1 = 0.f, puu2 = 0.f;
  float pc01 = 0.f, pc02 = 0.f, pc12 = 0.f;
  const int vbase = blockIdx.x * 32 + wave * 8;
  for (int r = 0; r < 8; r++) {
    int v = vbase + r;
    float4 a0 = E4[v * 128 + lane];
    float4 a1 = E4[v * 128 + 64 + lane];
    float acc[9];
#pragma unroll
    for (int j = 0; j < 9; j++) {
      float4 p = nr0[j], q = nr1[j];
      acc[j] = a0.x * p.x + a0.y * p.y + a0.z * p.z + a0.w * p.w +
               a1.x * q.x + a1.y * q.y + a1.z * q.z + a1.w * q.w;
    }
#pragma unroll
    for (int j = 0; j < 9; j++) {
      float a = acc[j];
#pragma unroll
      for (int off = 32; off; off >>= 1) a += __shfl_down(a, off, 64);
      acc[j] = a;
    }
    if (lane == 0) {
      float b0 = w9[0] * acc[0] * acc[0] + w9[1] * acc[1] * acc[1] + w9[2] * acc[2] * acc[2];
      float b1 = w9[3] * acc[3] * acc[3] + w9[4] * acc[4] * acc[4] + w9[5] * acc[5] * acc[5];
      float b2 = w9[6] * acc[6] * acc[6] + w9[7] * acc[7] * acc[7] + w9[8] * acc[8] * acc[8];
      born[v] = b0; born[VOCAB + v] = b1; born[2 * VOCAB + v] = b2;
      float u0 = expf(b0), u1 = expf(b1), u2 = expf(b2);
      pu0 += u0; pu1 += u1; pu2 += u2;
      pub0 += u0 * b0; pub1 += u1 * b1; pub2 += u2 * b2;
      puu0 += u0 * u0; puu1 += u1 * u1; puu2 += u2 * u2;
      pc01 += u0 * u1; pc02 += u0 * u2; pc12 += u1 * u2;
    }
  }
  if (lane == 0) {
    sb2[0][wave] = pu0;  sb2[1][wave] = pu1;  sb2[2][wave] = pu2;
    sb2[3][wave] = pub0; sb2[4][wave] = pub1; sb2[5][wave] = pub2;
    sb2[6][wave] = puu0; sb2[7][wave] = puu1; sb2[8][wave] = puu2;
    sb2[9][wave] = pc01; sb2[10][wave] = pc02; sb2[11][wave] = pc12;
  }
  __syncthreads();
  if (tid < 12) {
    float s = sb2[tid][0] + sb2[tid][1] + sb2[tid][2] + sb2[tid][3];
    ws[WS_PART + tid * 1024 + blockIdx.x] = s;
  }
  if (blockIdx.x == 0 && tid < 180) {     // Gram: 45 pairs x 4 lanes
    const int p = tid >> 2, sub = tid & 3;
    const float4* ni = N4 + (int)PI9[p] * 128;
    const float4* nj = N4 + (int)PJ9[p] * 128;
    float s = 0.f;
#pragma unroll
    for (int it = 0; it < 32; it++) {
      float4 a = ni[sub * 32 + it];
      float4 b = nj[sub * 32 + it];
      s += a.x * b.x + a.y * b.y + a.z * b.z + a.w * b.w;
    }
    s += __shfl_down(s, 2, 4);
    s += __shfl_down(s, 1, 4);
    if (sub == 0) ws[WS_G + p] = s;
  }

  // ---- last man of 1024 blocks: scalar chain + Jacobi ----
  __threadfence();
  if (tid == 0) {
    int old = atomicAdd(((int*)(ws + WS_CNT)) + (12 + t), 1);
    s_last = (old == 1023);
  }
  __syncthreads();
  if (!s_last) return;
  __threadfence();
#pragma unroll
  for (int jj = 0; jj < 3; jj++) {
    const int j = wave * 3 + jj;
    const float* src = ws + WS_PART + j * 1024;
    float s = 0.f;
#pragma unroll
    for (int b = 0; b < 16; b++) s += src[lane + b * 64];
#pragma unroll
    for (int off = 32; off; off >>= 1) s += __shfl_down(s, off, 64);
    if (lane == 0) r12[j] = s;
  }
  __syncthreads();
  if (tid != 0) return;
  float S0 = r12[0], S1 = r12[1], S2 = r12[2];
  float lg0 = logf(S0), lg1 = logf(S1), lg2 = logf(S2);
  float H0 = lg0 - r12[3] / S0;
  float H1 = lg1 - r12[4] / S1;
  float H2 = lg2 - r12[5] / S2;
  float c0 = 1.0f - H0 / MAX_ENT_F;
  float c1 = 1.0f - H1 / MAX_ENT_F;
  float c2 = 1.0f - H2 / MAX_ENT_F;
  float np0 = sqrtf(r12[6]) / S0 + 1e-10f;
  float np1 = sqrtf(r12[7]) / S1 + 1e-10f;
  float np2 = sqrtf(r12[8]) / S2 + 1e-10f;
  float A01 = (r12[9]  / (S0 * S1)) / (np0 * np1);
  float A02 = (r12[10] / (S0 * S2)) / (np0 * np2);
  float A12 = (r12[11] / (S1 * S2)) / (np1 * np2);
  float ag0 = 0.5f * (A01 + A02);
  float ag1 = 0.5f * (A01 + A12);
  float ag2 = 0.5f * (A02 + A12);
  float temp = fmaxf(fabsf(temp_p[0]), 0.01f);
  float z0 = c0 * ag0 / temp, z1 = c1 * ag1 / temp, z2 = c2 * ag2 / temp;
  float mz = fmaxf(z0, fmaxf(z1, z2));
  float e0 = expf(z0 - mz), e1 = expf(z1 - mz), e2 = expf(z2 - mz);
  float sd = e0 + e1 + e2;
  float wm0 = e0 / sd, wm1 = e1 / sd, wm2 = e2 / sd;
  float* slot = ws + WS_SLOT + (size_t)t * 32;
  o_w[0] = wm0; o_w[1] = wm1; o_w[2] = wm2;
  slot[0] = wm0; slot[1] = wm1; slot[2] = wm2;
  slot[3] = lg0; slot[4] = lg1; slot[5] = lg2;
  float cf0 = wm0 * ws[WS_WBUB + 0], cf1 = wm0 * ws[WS_WBUB + 1], cf2 = wm0 * ws[WS_WBUB + 2];
  float cf3 = wm1 * ws[WS_WBUB + 3], cf4 = wm1 * ws[WS_WBUB + 4], cf5 = wm1 * ws[WS_WBUB + 5];
  float cf6 = wm2 * ws[WS_WBUB + 6], cf7 = wm2 * ws[WS_WBUB + 7], cf8 = wm2 * ws[WS_WBUB + 8];
  slot[6] = cf0; slot[7] = cf1; slot[8] = cf2;
  slot[9] = cf3; slot[10] = cf4; slot[11] = cf5;
  slot[12] = cf6; slot[13] = cf7; slot[14] = cf8;
  float sq0 = sqrtf(cf0), sq1 = sqrtf(cf1), sq2 = sqrtf(cf2);
  float sq3 = sqrtf(cf3), sq4 = sqrtf(cf4), sq5 = sqrtf(cf5);
  float sq6 = sqrtf(cf6), sq7 = sqrtf(cf7), sq8 = sqrtf(cf8);
  const float* Gg = ws + WS_G;
  float m00=sq0*sq0*Gg[0],  m01=sq0*sq1*Gg[1],  m02=sq0*sq2*Gg[2],  m03=sq0*sq3*Gg[3],  m04=sq0*sq4*Gg[4];
  float m05=sq0*sq5*Gg[5],  m06=sq0*sq6*Gg[6],  m07=sq0*sq7*Gg[7],  m08=sq0*sq8*Gg[8];
  float m11=sq1*sq1*Gg[9],  m12=sq1*sq2*Gg[10], m13=sq1*sq3*Gg[11], m14=sq1*sq4*Gg[12];
  float m15=sq1*sq5*Gg[13], m16=sq1*sq6*Gg[14], m17=sq1*sq7*Gg[15], m18=sq1*sq8*Gg[16];
  float m22=sq2*sq2*Gg[17], m23=sq2*sq3*Gg[18], m24=sq2*sq4*Gg[19], m25=sq2*sq5*Gg[20];
  float m26=sq2*sq6*Gg[21], m27=sq2*sq7*Gg[22], m28=sq2*sq8*Gg[23];
  float m33=sq3*sq3*Gg[24], m34=sq3*sq4*Gg[25], m35=sq3*sq5*Gg[26], m36=sq3*sq6*Gg[27];
  float m37=sq3*sq7*Gg[28], m38=sq3*sq8*Gg[29];
  float m44=sq4*sq4*Gg[30], m45=sq4*sq5*Gg[31], m46=sq4*sq6*Gg[32], m47=sq4*sq7*Gg[33];
  float m48=sq4*sq8*Gg[34];
  float m55=sq5*sq5*Gg[35], m56=sq5*sq6*Gg[36], m57=sq5*sq7*Gg[37], m58=sq5*sq8*Gg[38];
  float m66=sq6*sq6*Gg[39], m67=sq6*sq7*Gg[40], m68=sq6*sq8*Gg[41];
  float m77=sq7*sq7*Gg[42], m78=sq7*sq8*Gg[43];
  float m88=sq8*sq8*Gg[44];
#pragma unroll 1
  for (int sweep = 0; sweep < 5; sweep++) {
    ROT(m00,m01,m11, m02,m12, m03,m13, m04,m14, m05,m15, m06,m16, m07,m17, m08,m18);
    ROT(m00,m02,m22, m01,m12, m03,m23, m04,m24, m05,m25, m06,m26, m07,m27, m08,m28);
    ROT(m00,m03,m33, m01,m13, m02,m23, m04,m34, m05,m35, m06,m36, m07,m37, m08,m38);
    ROT(m00,m04,m44, m01,m14, m02,m24, m03,m34, m05,m45, m06,m46, m07,m47, m08,m48);
    ROT(m00,m05,m55, m01,m15, m02,m25, m03,m35, m04,m45, m06,m56, m07,m57, m08,m58);
    ROT(m00,m06,m66, m01,m16, m02,m26, m03,m36, m04,m46, m05,m56, m07,m67, m08,m68);
    ROT(m00,m07,m77, m01,m17, m02,m27, m03,m37, m04,m47, m05,m57, m06,m67, m08,m78);
    ROT(m00,m08,m88, m01,m18, m02,m28, m03,m38, m04,m48, m05,m58, m06,m68, m07,m78);
    ROT(m11,m12,m22, m01,m02, m13,m23, m14,m24, m15,m25, m16,m26, m17,m27, m18,m28);
    ROT(m11,m13,m33, m01,m03, m12,m23, m14,m34, m15,m35, m16,m36, m17,m37, m18,m38);
    ROT(m11,m14,m44, m01,m04, m12,m24, m13,m34, m15,m45, m16,m46, m17,m47, m18,m48);
    ROT(m11,m15,m55, m01,m05, m12,m25, m13,m35, m14,m45, m16,m56, m17,m57, m18,m58);
    ROT(m11,m16,m66, m01,m06, m12,m26, m13,m36, m14,m46, m15,m56, m17,m67, m18,m68);
    ROT(m11,m17,m77, m01,m07, m12,m27, m13,m37, m14,m47, m15,m57, m16,m67, m18,m78);
    ROT(m11,m18,m88, m01,m08, m12,m28, m13,m38, m14,m48, m15,m58, m16,m68, m17,m78);
    ROT(m22,m23,m33, m02,m03, m12,m13, m24,m34, m25,m35, m26,m36, m27,m37, m28,m38);
    ROT(m22,m24,m44, m02,m04, m12,m14, m23,m34, m25,m45, m26,m46, m27,m47, m28,m48);
    ROT(m22,m25,m55, m02,m05, m12,m15, m23,m35, m24,m45, m26,m56, m27,m57, m28,m58);
    ROT(m22,m26,m66, m02,m06, m12,m16, m23,m36, m24,m46, m25,m56, m27,m67, m28,m68);
    ROT(m22,m27,m77, m02,m07, m12,m17, m23,m37, m24,m47, m25,m57, m26,m67, m28,m78);
    ROT(m22,m28,m88, m02,m08, m12,m18, m23,m38, m24,m48, m25,m58, m26,m68, m27,m78);
    ROT(m33,m34,m44, m03,m04, m13,m14, m23,m24, m35,m45, m36,m46, m37,m47, m38,m48);
    ROT(m33,m35,m55, m03,m05, m13,m15, m23,m25, m34,m45, m36,m56, m37,m57, m38,m58);
    ROT(m33,m36,m66, m03,m06, m13,m16, m23,m26, m34,m46, m35,m56, m37,m67, m38,m68);
    ROT(m33,m37,m77, m03,m07, m13,m17, m23,m27, m34,m47, m35,m57, m36,m67, m38,m78);
    ROT(m33,m38,m88, m03,m08, m13,m18, m23,m28, m34,m48, m35,m58, m36,m68, m37,m78);
    ROT(m44,m45,m55, m04,m05, m14,m15, m24,m25, m34,m35, m46,m56, m47,m57, m48,m58);
    ROT(m44,m46,m66, m04,m06, m14,m16, m24,m26, m34,m36, m45,m56, m47,m67, m48,m68);
    ROT(m44,m47,m77, m04,m07, m14,m17, m24,m27, m34,m37, m45,m57, m46,m67, m48,m78);
    ROT(m44,m48,m88, m04,m08, m14,m18, m24,m28, m34,m38, m45,m58, m46,m68, m47,m78);
    ROT(m55,m56,m66, m05,m06, m15,m16, m25,m26, m35,m36, m45,m46, m57,m67, m58,m68);
    ROT(m55,m57,m77, m05,m07, m15,m17, m25,m27, m35,m37, m45,m47, m56,m67, m58,m78);
    ROT(m55,m58,m88, m05,m08, m15,m18, m25,m28, m35,m38, m45,m48, m56,m68, m57,m78);
    ROT(m66,m67,m77, m06,m07, m16,m17, m26,m27, m36,m37, m46,m47, m56,m57, m68,m78);
    ROT(m66,m68,m88, m06,m08, m16,m18, m26,m28, m36,m38, m46,m48, m56,m58, m67,m78);
    ROT(m77,m78,m88, m07,m08, m17,m18, m27,m28, m37,m38, m47,m48, m57,m58, m67,m68);
  }
  float total = 503.0f * 1e-12f;
  float ev0 = fmaxf(m00, 1e-12f), ev1 = fmaxf(m11, 1e-12f), ev2 = fmaxf(m22, 1e-12f);
  float ev3 = fmaxf(m33, 1e-12f), ev4 = fmaxf(m44, 1e-12f), ev5 = fmaxf(m55, 1e-12f);
  float ev6 = fmaxf(m66, 1e-12f), ev7 = fmaxf(m77, 1e-12f), ev8 = fmaxf(m88, 1e-12f);
  total += ev0 + ev1 + ev2 + ev3 + ev4 + ev5 + ev6 + ev7 + ev8;
  float S = 0.f;
#define ENT(EV) do { float q_ = (EV) / total; S -= q_ * fmaxf(logf(q_), -100.0f); } while (0)
  ENT(ev0); ENT(ev1); ENT(ev2); ENT(ev3); ENT(ev4); ENT(ev5); ENT(ev6); ENT(ev7); ENT(ev8);
#undef ENT
  float q0 = 1e-12f / total;
  S -= 503.0f * (q0 * fmaxf(logf(q0), -100.0f));
  o_sr[0] = S;
  slot[16] = S;
}

// ---------------- kC: 512 rho rows + 128 token blocks; last-man -> logSt,H,F
__global__ __launch_bounds__(256) void kC(float* __restrict__ ws,
        float* __restrict__ rho, float* __restrict__ o_d,
        float* __restrict__ o_h, float* __restrict__ o_f, int t) {
  const int tid = threadIdx.x;
  __shared__ float cr[9];
  __shared__ float sc[6];
  __shared__ float red[16];
  __shared__ int s_last;
  float* slot = ws + WS_SLOT + (size_t)t * 32;
  if (blockIdx.x < 512) {
    const float* normed = ws + WS_NORMED;
    const int i = blockIdx.x;
    if (tid < 9) cr[tid] = slot[6 + tid] * normed[tid * DD + i];
    __syncthreads();
    for (int j = tid; j < DD; j += 256) {
      float s = 0.f;
#pragma unroll
      for (int k = 0; k < 9; k++) s += cr[k] * normed[k * DD + j];
      rho[i * DD + j] = s;
    }
    return;
  }
  if (tid < 3) { sc[tid] = slot[3 + tid]; sc[3 + tid] = slot[tid]; }  // logSf, wmeta
  __syncthreads();
  const int bi = blockIdx.x - 512;
  const int v = bi * 256 + tid;
  const float* born = ws + WS_BORN;
  float b0 = born[v], b1 = born[VOCAB + v], b2 = born[2 * VOCAB + v];
  o_d[v]             = expf(b0 - sc[0]);
  o_d[VOCAB + v]     = expf(b1 - sc[1]);
  o_d[2 * VOCAB + v] = expf(b2 - sc[2]);
  float s = sc[3] * b0 + sc[4] * b1 + sc[5] * b2;
  float e = expf(s);
  float se  = blockReduceSum(e, red);
  float ses = blockReduceSum(e * s, red);
  float* wt = ws + WS_WT;
  if (tid == 0) { wt[bi] = se; wt[128 + bi] = ses; }
  __threadfence();
  if (tid == 0) {
    int old = atomicAdd(((int*)(ws + WS_CNT)) + (16 + t), 1);
    s_last = (old == 127);
  }
  __syncthreads();
  if (!s_last) return;
  __threadfence();
  float a_in = (tid < 128) ? wt[tid] : 0.f;
  float b_in = (tid < 128) ? wt[128 + tid] : 0.f;
  float A = blockReduceSum(a_in, red);
  float B = blockReduceSum(b_in, red);
  if (tid == 0) {
    float lgS = logf(A);
    slot[15] = lgS;
    float H = lgS - B / A;
    o_h[0] = H;
    o_f[0] = H - slot[16];
  }
}

// ---------------- tail: o_tok for the final step
__global__ __launch_bounds__(256) void k_tok(const float* __restrict__ ws,
        const float* __restrict__ o_d_prev, float* __restrict__ o_tok_prev, int tprev) {
  const int tid = threadIdx.x;
  __shared__ float sc[7];
  const float* slot = ws + WS_SLOT + (size_t)tprev * 32;
  if (tid < 6) sc[tid] = slot[tid];
  if (tid == 6) sc[6] = slot[15];
  __syncthreads();
  const int v = blockIdx.x * 256 + tid;
  float C = sc[0] * sc[3] + sc[1] * sc[4] + sc[2] * sc[5] - sc[6];
  float s = sc[0] * logf(o_d_prev[v]) + sc[1] * logf(o_d_prev[VOCAB + v]) +
            sc[2] * logf(o_d_prev[2 * VOCAB + v]);
  o_tok_prev[v] = expf(s + C);
}

// ---------------- host launcher ----------------
extern "C" void kernel_launch(void* const* d_in, const int* in_sizes, int n_in,
                              void* d_out, int out_size, void* d_ws, size_t ws_size,
                              hipStream_t stream) {
  const int*   tokens = (const int*)d_in[0];
  const float* E      = (const float*)d_in[1];
  const float* Ws     = (const float*)d_in[2];
  const float* temp_p = (const float*)d_in[3];
  const float* base_p = (const float*)d_in[4];
  const float* sens_p = (const float*)d_in[5];

  float* out   = (float*)d_out;
  float* o_tok = out;                             // [4][32768]
  float* o_rho = o_tok + SEQ * VOCAB;             // [4][512][512]
  float* o_w   = o_rho + (size_t)SEQ * DD * DD;   // [4][3]
  float* o_sr  = o_w + SEQ * NF;                  // [4]
  float* o_h   = o_sr + SEQ;                      // [4]
  float* o_f   = o_h + SEQ;                       // [4]
  float* o_d   = o_f + SEQ;                       // [4][3][32768]

  float* ws = (float*)d_ws;

  k_init<<<18, 256, 0, stream>>>(ws);

  for (int t = 0; t < SEQ; t++) {
    float* otp = (t > 0) ? (o_tok + (size_t)(t - 1) * VOCAB) : o_tok;
    const float* odp = (t > 0) ? (o_d + (size_t)(t - 1) * NF * VOCAB) : o_d;
    kA<<<(t > 0) ? 200 : 72, 256, 0, stream>>>(tokens, E, Ws, base_p, sens_p,
                                               ws, otp, odp, t);
    kB<<<1024, 256, 0, stream>>>((const float4*)E, ws, temp_p,
                                 o_w + t * NF, o_sr + t, t);
    kC<<<640, 256, 0, stream>>>(ws, o_rho + (size_t)t * DD * DD,
                                o_d + (size_t)t * NF * VOCAB, o_h + t, o_f + t, t);
  }
  k_tok<<<128, 256, 0, stream>>>(ws, o_d + (size_t)3 * NF * VOCAB,
                                 o_tok + (size_t)3 * VOCAB, 3);
}

// Round 8
// 454.905 us; speedup vs baseline: 1.9537x; 1.9537x over previous
//
#include <hip/hip_runtime.h>
#include <math.h>

#define VOCAB 32768
#define DD 512
#define NB 3
#define NF 3
#define SEQ 4
#define MAX_ENT_F 10.3972077083991790f

// ---- ws layout (floats) ----
#define WS_MEM    0        // [9][512] = 4608 (zeroed by k_init)
#define WS_WBUB   4616     // [9]
#define WS_NORMED 4640     // [9][512] (16B aligned)
#define WS_SLOT   9248     // [4][32]: 0-2 wmeta, 3-5 logSf, 6-14 coeff, 16 srho
#define WS_CNT    9376     // 32 ints (zeroed by k_init): [t*3+f] for kA equil
#define WS_G      9472     // [45] Gram
#define WS_WT     9536     // [4][256] token partials
#define WS_PART   10752    // [12][2048] born-moment partials
#define WS_BORN   35840    // [3][VOCAB] (16B aligned)
#define WS_STP    135168   // [9][8][512] states partials

// pair index tables for i<=j over 9 (45 pairs)
__device__ const unsigned char PI9[45] = {
  0,0,0,0,0,0,0,0,0, 1,1,1,1,1,1,1,1, 2,2,2,2,2,2,2, 3,3,3,3,3,3,
  4,4,4,4,4, 5,5,5,5, 6,6,6, 7,7, 8};
__device__ const unsigned char PJ9[45] = {
  0,1,2,3,4,5,6,7,8, 1,2,3,4,5,6,7,8, 2,3,4,5,6,7,8, 3,4,5,6,7,8,
  4,5,6,7,8, 5,6,7,8, 6,7,8, 7,8, 8};

__device__ __forceinline__ float blockReduceSum(float v, float* sh) {
  int lane = threadIdx.x & 63;
  int wid  = threadIdx.x >> 6;
#pragma unroll
  for (int off = 32; off; off >>= 1) v += __shfl_down(v, off, 64);
  __syncthreads();
  if (lane == 0) sh[wid] = v;
  __syncthreads();
  int nw = blockDim.x >> 6;
  float r = 0.0f;
  if ((int)threadIdx.x < nw) r = sh[threadIdx.x];
  if (wid == 0) {
#pragma unroll
    for (int off = 8; off; off >>= 1) r += __shfl_down(r, off, 64);
    if (lane == 0) sh[0] = r;
  }
  __syncthreads();
  return sh[0];
}

__global__ void k_init(float* __restrict__ ws) {
  int i = blockIdx.x * 256 + threadIdx.x;
  if (i < NF * NB * DD) ws[WS_MEM + i] = 0.0f;
  if (i < 32) ((int*)(ws + WS_CNT))[i] = 0;
}

// ---------------- kA: blocks 0-71 states partials + last-man equil;
// blocks >=72 (t>0): token pass for step t-1 (re-reduce wt; no fences needed).
__global__ __launch_bounds__(256) void kA(const int* __restrict__ tokens,
        const float* __restrict__ E, const float* __restrict__ Ws,
        const float* __restrict__ base_p, const float* __restrict__ sens_p,
        float* __restrict__ ws, const float* __restrict__ o_d_prev,
        float* __restrict__ o_tok_prev, float* __restrict__ o_h_prev,
        float* __restrict__ o_f_prev, int t) {
  const int tid = threadIdx.x;
  __shared__ float red[16];

  if (blockIdx.x >= 72) {
    // ---- token pass for t-1: every block re-reduces wt (256 values) ----
    __shared__ float sc[6];
    const float* slot = ws + WS_SLOT + (size_t)(t - 1) * 32;
    if (tid < 6) sc[tid] = slot[tid];          // 0-2 wmeta, 3-5 logSf
    const float* wt = ws + WS_WT + (size_t)(t - 1) * 256;
    float a_in = (tid < 128) ? wt[tid] : 0.f;
    float b_in = (tid < 128) ? wt[128 + tid] : 0.f;
    float A = blockReduceSum(a_in, red);
    float B = blockReduceSum(b_in, red);
    float lgS = logf(A);
    const int bi = blockIdx.x - 72;
    const int v = bi * 256 + tid;
    float C = sc[0] * sc[3] + sc[1] * sc[4] + sc[2] * sc[5] - lgS;
    float s = sc[0] * logf(o_d_prev[v]) + sc[1] * logf(o_d_prev[VOCAB + v]) +
              sc[2] * logf(o_d_prev[2 * VOCAB + v]);
    o_tok_prev[v] = expf(s + C);
    if (bi == 0 && tid == 0) {
      float H = lgS - B / A;
      o_h_prev[0] = H;
      o_f_prev[0] = H - slot[16];
    }
    return;
  }

  // ---- states GEMV partial: fn = b/8, dc = b%8 ----
  __shared__ float smean[DD];
  __shared__ float xin_loc[64];
  __shared__ float s_decay;
  __shared__ int s_last;
  __shared__ float seq[NB * DD];
  __shared__ float snrm[NB];
  const int fn = blockIdx.x >> 3, dc = blockIdx.x & 7;
  const int f = fn / NB;
  const int d0 = dc * 64;
  float* mem = ws + WS_MEM;
  const float* x = E + (size_t)tokens[t] * DD;
  const float* m = mem + f * (NB * DD);
  for (int d = tid; d < DD; d += 256)
    smean[d] = (m[d] + m[DD + d] + m[2 * DD + d]) * (1.0f / 3.0f);
  __syncthreads();
  float pxm = 0.f, pxx = 0.f, pmm = 0.f;
  for (int d = tid; d < DD; d += 256) {
    float xv = x[d], mv = smean[d];
    pxm += xv * mv; pxx += xv * xv; pmm += mv * mv;
  }
  float sxm = blockReduceSum(pxm, red);
  float sxx = blockReduceSum(pxx, red);
  float smm = blockReduceSum(pmm, red);
  if (tid == 0) {
    float mem_norm = sqrtf(smm) + 1e-10f;
    float x_norm   = sqrtf(sxx) + 1e-10f;
    float novelty  = (mem_norm > 1e-8f) ? (1.0f - sxm / (x_norm * mem_norm)) : 1.0f;
    float sens = fabsf(sens_p[0]);
    float z = base_p[0] - sens * novelty;
    s_decay = 1.0f / (1.0f + expf(-z));
  }
  __syncthreads();
  if (tid < 64) xin_loc[tid] = x[d0 + tid] + s_decay * smean[d0 + tid];
  __syncthreads();
  const float* W = Ws + (size_t)fn * DD * DD + (size_t)d0 * DD;
  float acc0 = 0.f, acc1 = 0.f;
#pragma unroll 8
  for (int dd = 0; dd < 64; dd++) {
    float xv = xin_loc[dd];
    acc0 += xv * W[dd * DD + tid];
    acc1 += xv * W[dd * DD + tid + 256];
  }
  float* o = ws + WS_STP + (fn * 8 + dc) * DD;
  o[tid] = acc0;
  o[tid + 256] = acc1;

  // ---- last man of this foam's 24 blocks runs equil (small fence count) ----
  __threadfence();
  if (tid == 0) {
    int old = atomicAdd(((int*)(ws + WS_CNT)) + (t * 3 + f), 1);
    s_last = (old == 23);
  }
  __syncthreads();
  if (!s_last) return;
  __threadfence();

  for (int i = tid; i < NB * DD; i += 256) {
    int n = i >> 9, e = i & 511;
    const float* src = ws + WS_STP + ((f * NB + n) * 8) * DD + e;
    float acc = 0.f;
#pragma unroll
    for (int c = 0; c < 8; c++) acc += src[c * DD];
    seq[i] = acc;
  }
  __syncthreads();
  for (int e = tid; e < DD; e += 256) {
    float a = seq[e], b = seq[DD + e], c = seq[2 * DD + e];
#pragma unroll
    for (int it = 0; it < 3; it++) {
      float mn = (a + b + c) * (1.0f / 3.0f);
      a += 0.3f * (mn - a);
      b += 0.3f * (mn - b);
      c += 0.3f * (mn - c);
    }
    seq[e] = a; seq[DD + e] = b; seq[2 * DD + e] = c;
  }
  __syncthreads();
  for (int n = 0; n < NB; n++) {
    float p = 0.f;
    for (int e = tid; e < DD; e += 256) { float v = seq[n * DD + e]; p += v * v; }
    float ss = blockReduceSum(p, red);
    if (tid == 0) snrm[n] = sqrtf(ss);
  }
  __syncthreads();
  if (tid == 0) {
    float n0 = snrm[0], n1 = snrm[1], n2 = snrm[2];
    float mx = fmaxf(2.0f * n0, fmaxf(2.0f * n1, 2.0f * n2));
    float e0 = expf(2.0f * n0 - mx), e1 = expf(2.0f * n1 - mx), e2 = expf(2.0f * n2 - mx);
    float sd = e0 + e1 + e2;
    ws[WS_WBUB + f * NB + 0] = e0 / sd;
    ws[WS_WBUB + f * NB + 1] = e1 / sd;
    ws[WS_WBUB + f * NB + 2] = e2 / sd;
  }
  float dec = s_decay;
  for (int i = tid; i < NB * DD; i += 256) {
    int n = i >> 9;
    float sv = seq[i];
    ws[WS_NORMED + f * NB * DD + i] = sv / (snrm[n] + 1e-10f);
    float old = mem[f * NB * DD + i];
    mem[f * NB * DD + i] = dec * old + (1.0f - dec) * sv;
  }
}

// ---------------- kB: born + moments + Gram (round-6 structure: NO fences,
// NO atomics, 2048 blocks x 4 rows/wave fully unrolled for load overlap)
__global__ __launch_bounds__(256) void kB(const float4* __restrict__ E4,
                                          float* __restrict__ ws) {
  const int tid = threadIdx.x, lane = tid & 63, wave = tid >> 6;
  const float4* N4 = (const float4*)(ws + WS_NORMED);
  float* born = ws + WS_BORN;
  float4 nr0[9], nr1[9];
#pragma unroll
  for (int j = 0; j < 9; j++) {
    nr0[j] = N4[j * 128 + lane];
    nr1[j] = N4[j * 128 + 64 + lane];
  }
  __shared__ float w9[9];
  __shared__ float sb2[12][4];
  if (tid < 9) w9[tid] = ws[WS_WBUB + tid];
  __syncthreads();
  float pu0 = 0.f, pu1 = 0.f, pu2 = 0.f;
  float pub0 = 0.f, pub1 = 0.f, pub2 = 0.f;
  float puu0 = 0.f, puu1 = 0.f, puu2 = 0.f;
  float pc01 = 0.f, pc02 = 0.f, pc12 = 0.f;
  const int vbase = blockIdx.x * 16 + wave * 4;
#pragma unroll
  for (int r = 0; r < 4; r++) {
    int v = vbase + r;
    float4 a0 = E4[v * 128 + lane];
    float4 a1 = E4[v * 128 + 64 + lane];
    float acc[9];
#pragma unroll
    for (int j = 0; j < 9; j++) {
      float4 p = nr0[j], q = nr1[j];
      acc[j] = a0.x * p.x + a0.y * p.y + a0.z * p.z + a0.w * p.w +
               a1.x * q.x + a1.y * q.y + a1.z * q.z + a1.w * q.w;
    }
#pragma unroll
    for (int j = 0; j < 9; j++) {
      float a = acc[j];
#pragma unroll
      for (int off = 32; off; off >>= 1) a += __shfl_down(a, off, 64);
      acc[j] = a;
    }
    if (lane == 0) {
      float b0 = w9[0] * acc[0] * acc[0] + w9[1] * acc[1] * acc[1] + w9[2] * acc[2] * acc[2];
      float b1 = w9[3] * acc[3] * acc[3] + w9[4] * acc[4] * acc[4] + w9[5] * acc[5] * acc[5];
      float b2 = w9[6] * acc[6] * acc[6] + w9[7] * acc[7] * acc[7] + w9[8] * acc[8] * acc[8];
      born[v] = b0; born[VOCAB + v] = b1; born[2 * VOCAB + v] = b2;
      float u0 = expf(b0), u1 = expf(b1), u2 = expf(b2);
      pu0 += u0; pu1 += u1; pu2 += u2;
      pub0 += u0 * b0; pub1 += u1 * b1; pub2 += u2 * b2;
      puu0 += u0 * u0; puu1 += u1 * u1; puu2 += u2 * u2;
      pc01 += u0 * u1; pc02 += u0 * u2; pc12 += u1 * u2;
    }
  }
  if (lane == 0) {
    sb2[0][wave] = pu0;  sb2[1][wave] = pu1;  sb2[2][wave] = pu2;
    sb2[3][wave] = pub0; sb2[4][wave] = pub1; sb2[5][wave] = pub2;
    sb2[6][wave] = puu0; sb2[7][wave] = puu1; sb2[8][wave] = puu2;
    sb2[9][wave] = pc01; sb2[10][wave] = pc02; sb2[11][wave] = pc12;
  }
  __syncthreads();
  if (tid < 12) {
    float s = sb2[tid][0] + sb2[tid][1] + sb2[tid][2] + sb2[tid][3];
    ws[WS_PART + tid * 2048 + blockIdx.x] = s;
  }
  if (blockIdx.x == 0 && tid < 180) {   // Gram: 45 pairs x 4 lanes
    const int p = tid >> 2, sub = tid & 3;
    const float4* ni = N4 + (int)PI9[p] * 128;
    const float4* nj = N4 + (int)PJ9[p] * 128;
    float s = 0.f;
#pragma unroll
    for (int it = 0; it < 32; it++) {
      float4 a = ni[sub * 32 + it];
      float4 b = nj[sub * 32 + it];
      s += a.x * b.x + a.y * b.y + a.z * b.z + a.w * b.w;
    }
    s += __shfl_down(s, 2, 4);
    s += __shfl_down(s, 1, 4);
    if (sub == 0) ws[WS_G + p] = s;
  }
}

// One Jacobi rotation on named scalars; HW rcp/rsq/sqrt keep the chain short.
#define ROT(APP,APQ,AQQ,P1,Q1,P2,Q2,P3,Q3,P4,Q4,P5,Q5,P6,Q6,P7,Q7) do {           \
    float apq_ = APQ;                                                               \
    float den_ = (fabsf(apq_) > 1e-25f) ? apq_ : 1e-25f;                            \
    float th_  = 0.5f * (AQQ - APP) * __builtin_amdgcn_rcpf(den_);                  \
    float mag_ = __builtin_amdgcn_rcpf(fabsf(th_) +                                 \
                   __builtin_amdgcn_sqrtf(th_ * th_ + 1.f));                        \
    float tt_  = copysignf(mag_, th_);                                              \
    float cc_  = __builtin_amdgcn_rsqf(tt_ * tt_ + 1.f);                            \
    float sn_  = tt_ * cc_;                                                         \
    APP -= tt_ * apq_;  AQQ += tt_ * apq_;  APQ = 0.0f;                             \
    float a_, b_;                                                                   \
    a_ = P1; b_ = Q1; P1 = cc_ * a_ - sn_ * b_; Q1 = sn_ * a_ + cc_ * b_;           \
    a_ = P2; b_ = Q2; P2 = cc_ * a_ - sn_ * b_; Q2 = sn_ * a_ + cc_ * b_;           \
    a_ = P3; b_ = Q3; P3 = cc_ * a_ - sn_ * b_; Q3 = sn_ * a_ + cc_ * b_;           \
    a_ = P4; b_ = Q4; P4 = cc_ * a_ - sn_ * b_; Q4 = sn_ * a_ + cc_ * b_;           \
    a_ = P5; b_ = Q5; P5 = cc_ * a_ - sn_ * b_; Q5 = sn_ * a_ + cc_ * b_;           \
    a_ = P6; b_ = Q6; P6 = cc_ * a_ - sn_ * b_; Q6 = sn_ * a_ + cc_ * b_;           \
    a_ = P7; b_ = Q7; P7 = cc_ * a_ - sn_ * b_; Q7 = sn_ * a_ + cc_ * b_;           \
  } while (0)

// ---------------- kS: one block reduces 12x2048 partials; lane 0 Jacobi
__global__ __launch_bounds__(256, 1) void kS(float* __restrict__ ws,
                                             const float* __restrict__ temp_p,
                                             float* __restrict__ o_w,
                                             float* __restrict__ o_sr, int t) {
  const int tid = threadIdx.x, lane = tid & 63, wave = tid >> 6;
  __shared__ float r12[12];
#pragma unroll
  for (int jj = 0; jj < 3; jj++) {
    const int j = wave * 3 + jj;
    const float* src = ws + WS_PART + j * 2048;
    float s = 0.f;
#pragma unroll
    for (int b = 0; b < 32; b++) s += src[lane + b * 64];
#pragma unroll
    for (int off = 32; off; off >>= 1) s += __shfl_down(s, off, 64);
    if (lane == 0) r12[j] = s;
  }
  __syncthreads();
  if (tid != 0) return;
  float S0 = r12[0], S1 = r12[1], S2 = r12[2];
  float lg0 = logf(S0), lg1 = logf(S1), lg2 = logf(S2);
  float H0 = lg0 - r12[3] / S0;
  float H1 = lg1 - r12[4] / S1;
  float H2 = lg2 - r12[5] / S2;
  float c0 = 1.0f - H0 / MAX_ENT_F;
  float c1 = 1.0f - H1 / MAX_ENT_F;
  float c2 = 1.0f - H2 / MAX_ENT_F;
  float np0 = sqrtf(r12[6]) / S0 + 1e-10f;
  float np1 = sqrtf(r12[7]) / S1 + 1e-10f;
  float np2 = sqrtf(r12[8]) / S2 + 1e-10f;
  float A01 = (r12[9]  / (S0 * S1)) / (np0 * np1);
  float A02 = (r12[10] / (S0 * S2)) / (np0 * np2);
  float A12 = (r12[11] / (S1 * S2)) / (np1 * np2);
  float ag0 = 0.5f * (A01 + A02);
  float ag1 = 0.5f * (A01 + A12);
  float ag2 = 0.5f * (A02 + A12);
  float temp = fmaxf(fabsf(temp_p[0]), 0.01f);
  float z0 = c0 * ag0 / temp, z1 = c1 * ag1 / temp, z2 = c2 * ag2 / temp;
  float mz = fmaxf(z0, fmaxf(z1, z2));
  float e0 = expf(z0 - mz), e1 = expf(z1 - mz), e2 = expf(z2 - mz);
  float sd = e0 + e1 + e2;
  float wm0 = e0 / sd, wm1 = e1 / sd, wm2 = e2 / sd;
  float* slot = ws + WS_SLOT + (size_t)t * 32;
  o_w[0] = wm0; o_w[1] = wm1; o_w[2] = wm2;
  slot[0] = wm0; slot[1] = wm1; slot[2] = wm2;
  slot[3] = lg0; slot[4] = lg1; slot[5] = lg2;
  float cf0 = wm0 * ws[WS_WBUB + 0], cf1 = wm0 * ws[WS_WBUB + 1], cf2 = wm0 * ws[WS_WBUB + 2];
  float cf3 = wm1 * ws[WS_WBUB + 3], cf4 = wm1 * ws[WS_WBUB + 4], cf5 = wm1 * ws[WS_WBUB + 5];
  float cf6 = wm2 * ws[WS_WBUB + 6], cf7 = wm2 * ws[WS_WBUB + 7], cf8 = wm2 * ws[WS_WBUB + 8];
  slot[6] = cf0; slot[7] = cf1; slot[8] = cf2;
  slot[9] = cf3; slot[10] = cf4; slot[11] = cf5;
  slot[12] = cf6; slot[13] = cf7; slot[14] = cf8;
  float sq0 = sqrtf(cf0), sq1 = sqrtf(cf1), sq2 = sqrtf(cf2);
  float sq3 = sqrtf(cf3), sq4 = sqrtf(cf4), sq5 = sqrtf(cf5);
  float sq6 = sqrtf(cf6), sq7 = sqrtf(cf7), sq8 = sqrtf(cf8);
  const float* Gg = ws + WS_G;
  float m00=sq0*sq0*Gg[0],  m01=sq0*sq1*Gg[1],  m02=sq0*sq2*Gg[2],  m03=sq0*sq3*Gg[3],  m04=sq0*sq4*Gg[4];
  float m05=sq0*sq5*Gg[5],  m06=sq0*sq6*Gg[6],  m07=sq0*sq7*Gg[7],  m08=sq0*sq8*Gg[8];
  float m11=sq1*sq1*Gg[9],  m12=sq1*sq2*Gg[10], m13=sq1*sq3*Gg[11], m14=sq1*sq4*Gg[12];
  float m15=sq1*sq5*Gg[13], m16=sq1*sq6*Gg[14], m17=sq1*sq7*Gg[15], m18=sq1*sq8*Gg[16];
  float m22=sq2*sq2*Gg[17], m23=sq2*sq3*Gg[18], m24=sq2*sq4*Gg[19], m25=sq2*sq5*Gg[20];
  float m26=sq2*sq6*Gg[21], m27=sq2*sq7*Gg[22], m28=sq2*sq8*Gg[23];
  float m33=sq3*sq3*Gg[24], m34=sq3*sq4*Gg[25], m35=sq3*sq5*Gg[26], m36=sq3*sq6*Gg[27];
  float m37=sq3*sq7*Gg[28], m38=sq3*sq8*Gg[29];
  float m44=sq4*sq4*Gg[30], m45=sq4*sq5*Gg[31], m46=sq4*sq6*Gg[32], m47=sq4*sq7*Gg[33];
  float m48=sq4*sq8*Gg[34];
  float m55=sq5*sq5*Gg[35], m56=sq5*sq6*Gg[36], m57=sq5*sq7*Gg[37], m58=sq5*sq8*Gg[38];
  float m66=sq6*sq6*Gg[39], m67=sq6*sq7*Gg[40], m68=sq6*sq8*Gg[41];
  float m77=sq7*sq7*Gg[42], m78=sq7*sq8*Gg[43];
  float m88=sq8*sq8*Gg[44];
#pragma unroll 1
  for (int sweep = 0; sweep < 5; sweep++) {
    ROT(m00,m01,m11, m02,m12, m03,m13, m04,m14, m05,m15, m06,m16, m07,m17, m08,m18);
    ROT(m00,m02,m22, m01,m12, m03,m23, m04,m24, m05,m25, m06,m26, m07,m27, m08,m28);
    ROT(m00,m03,m33, m01,m13, m02,m23, m04,m34, m05,m35, m06,m36, m07,m37, m08,m38);
    ROT(m00,m04,m44, m01,m14, m02,m24, m03,m34, m05,m45, m06,m46, m07,m47, m08,m48);
    ROT(m00,m05,m55, m01,m15, m02,m25, m03,m35, m04,m45, m06,m56, m07,m57, m08,m58);
    ROT(m00,m06,m66, m01,m16, m02,m26, m03,m36, m04,m46, m05,m56, m07,m67, m08,m68);
    ROT(m00,m07,m77, m01,m17, m02,m27, m03,m37, m04,m47, m05,m57, m06,m67, m08,m78);
    ROT(m00,m08,m88, m01,m18, m02,m28, m03,m38, m04,m48, m05,m58, m06,m68, m07,m78);
    ROT(m11,m12,m22, m01,m02, m13,m23, m14,m24, m15,m25, m16,m26, m17,m27, m18,m28);
    ROT(m11,m13,m33, m01,m03, m12,m23, m14,m34, m15,m35, m16,m36, m17,m37, m18,m38);
    ROT(m11,m14,m44, m01,m04, m12,m24, m13,m34, m15,m45, m16,m46, m17,m47, m18,m48);
    ROT(m11,m15,m55, m01,m05, m12,m25, m13,m35, m14,m45, m16,m56, m17,m57, m18,m58);
    ROT(m11,m16,m66, m01,m06, m12,m26, m13,m36, m14,m46, m15,m56, m17,m67, m18,m68);
    ROT(m11,m17,m77, m01,m07, m12,m27, m13,m37, m14,m47, m15,m57, m16,m67, m18,m78);
    ROT(m11,m18,m88, m01,m08, m12,m28, m13,m38, m14,m48, m15,m58, m16,m68, m17,m78);
    ROT(m22,m23,m33, m02,m03, m12,m13, m24,m34, m25,m35, m26,m36, m27,m37, m28,m38);
    ROT(m22,m24,m44, m02,m04, m12,m14, m23,m34, m25,m45, m26,m46, m27,m47, m28,m48);
    ROT(m22,m25,m55, m02,m05, m12,m15, m23,m35, m24,m45, m26,m56, m27,m57, m28,m58);
    ROT(m22,m26,m66, m02,m06, m12,m16, m23,m36, m24,m46, m25,m56, m27,m67, m28,m68);
    ROT(m22,m27,m77, m02,m07, m12,m17, m23,m37, m24,m47, m25,m57, m26,m67, m28,m78);
    ROT(m22,m28,m88, m02,m08, m12,m18, m23,m38, m24,m48, m25,m58, m26,m68, m27,m78);
    ROT(m33,m34,m44, m03,m04, m13,m14, m23,m24, m35,m45, m36,m46, m37,m47, m38,m48);
    ROT(m33,m35,m55, m03,m05, m13,m15, m23,m25, m34,m45, m36,m56, m37,m57, m38,m58);
    ROT(m33,m36,m66, m03,m06, m13,m16, m23,m26, m34,m46, m35,m56, m37,m67, m38,m68);
    ROT(m33,m37,m77, m03,m07, m13,m17, m23,m27, m34,m47, m35,m57, m36,m67, m38,m78);
    ROT(m33,m38,m88, m03,m08, m13,m18, m23,m28, m34,m48, m35,m58, m36,m68, m37,m78);
    ROT(m44,m45,m55, m04,m05, m14,m15, m24,m25, m34,m35, m46,m56, m47,m57, m48,m58);
    ROT(m44,m46,m66, m04,m06, m14,m16, m24,m26, m34,m36, m45,m56, m47,m67, m48,m68);
    ROT(m44,m47,m77, m04,m07, m14,m17, m24,m27, m34,m37, m45,m57, m46,m67, m48,m78);
    ROT(m44,m48,m88, m04,m08, m14,m18, m24,m28, m34,m38, m45,m58, m46,m68, m47,m78);
    ROT(m55,m56,m66, m05,m06, m15,m16, m25,m26, m35,m36, m45,m46, m57,m67, m58,m68);
    ROT(m55,m57,m77, m05,m07, m15,m17, m25,m27, m35,m37, m45,m47, m56,m67, m58,m78);
    ROT(m55,m58,m88, m05,m08, m15,m18, m25,m28, m35,m38, m45,m48, m56,m68, m57,m78);
    ROT(m66,m67,m77, m06,m07, m16,m17, m26,m27, m36,m37, m46,m47, m56,m57, m68,m78);
    ROT(m66,m68,m88, m06,m08, m16,m18, m26,m28, m36,m38, m46,m48, m56,m58, m67,m78);
    ROT(m77,m78,m88, m07,m08, m17,m18, m27,m28, m37,m38, m47,m48, m57,m58, m67,m68);
  }
  float total = 503.0f * 1e-12f;
  float ev0 = fmaxf(m00, 1e-12f), ev1 = fmaxf(m11, 1e-12f), ev2 = fmaxf(m22, 1e-12f);
  float ev3 = fmaxf(m33, 1e-12f), ev4 = fmaxf(m44, 1e-12f), ev5 = fmaxf(m55, 1e-12f);
  float ev6 = fmaxf(m66, 1e-12f), ev7 = fmaxf(m77, 1e-12f), ev8 = fmaxf(m88, 1e-12f);
  total += ev0 + ev1 + ev2 + ev3 + ev4 + ev5 + ev6 + ev7 + ev8;
  float S = 0.f;
#define ENT(EV) do { float q_ = (EV) / total; S -= q_ * fmaxf(logf(q_), -100.0f); } while (0)
  ENT(ev0); ENT(ev1); ENT(ev2); ENT(ev3); ENT(ev4); ENT(ev5); ENT(ev6); ENT(ev7); ENT(ev8);
#undef ENT
  float q0 = 1e-12f / total;
  S -= 503.0f * (q0 * fmaxf(logf(q0), -100.0f));
  o_sr[0] = S;
  slot[16] = S;
}

// ---------------- kC: blocks <512 rho rows; blocks >=512 write o_d + wt
__global__ __launch_bounds__(256) void kC(float* __restrict__ ws,
        float* __restrict__ rho, float* __restrict__ o_d, int t) {
  const int tid = threadIdx.x;
  float* slot = ws + WS_SLOT + (size_t)t * 32;
  if (blockIdx.x < 512) {
    __shared__ float cr[9];
    const float* normed = ws + WS_NORMED;
    const int i = blockIdx.x;
    if (tid < 9) cr[tid] = slot[6 + tid] * normed[tid * DD + i];
    __syncthreads();
    for (int j = tid; j < DD; j += 256) {
      float s = 0.f;
#pragma unroll
      for (int k = 0; k < 9; k++) s += cr[k] * normed[k * DD + j];
      rho[i * DD + j] = s;
    }
    return;
  }
  __shared__ float sc[6];
  __shared__ float red[16];
  if (tid < 3) { sc[tid] = slot[3 + tid]; sc[3 + tid] = slot[tid]; }  // logSf, wmeta
  __syncthreads();
  const int bi = blockIdx.x - 512;
  const int v = bi * 256 + tid;
  const float* born = ws + WS_BORN;
  float b0 = born[v], b1 = born[VOCAB + v], b2 = born[2 * VOCAB + v];
  o_d[v]             = expf(b0 - sc[0]);
  o_d[VOCAB + v]     = expf(b1 - sc[1]);
  o_d[2 * VOCAB + v] = expf(b2 - sc[2]);
  float s = sc[3] * b0 + sc[4] * b1 + sc[5] * b2;
  float e = expf(s);
  float se  = blockReduceSum(e, red);
  float ses = blockReduceSum(e * s, red);
  float* wt = ws + WS_WT + (size_t)t * 256;
  if (tid == 0) { wt[bi] = se; wt[128 + bi] = ses; }
}

// ---------------- tail: token pass + H/F for the final step
__global__ __launch_bounds__(256) void k_tok(float* __restrict__ ws,
        const float* __restrict__ o_d_prev, float* __restrict__ o_tok_prev,
        float* __restrict__ o_h_prev, float* __restrict__ o_f_prev, int tprev) {
  const int tid = threadIdx.x;
  __shared__ float sc[6];
  __shared__ float red[16];
  const float* slot = ws + WS_SLOT + (size_t)tprev * 32;
  if (tid < 6) sc[tid] = slot[tid];
  const float* wt = ws + WS_WT + (size_t)tprev * 256;
  float a_in = (tid < 128) ? wt[tid] : 0.f;
  float b_in = (tid < 128) ? wt[128 + tid] : 0.f;
  float A = blockReduceSum(a_in, red);
  float B = blockReduceSum(b_in, red);
  float lgS = logf(A);
  const int v = blockIdx.x * 256 + tid;
  float C = sc[0] * sc[3] + sc[1] * sc[4] + sc[2] * sc[5] - lgS;
  float s = sc[0] * logf(o_d_prev[v]) + sc[1] * logf(o_d_prev[VOCAB + v]) +
            sc[2] * logf(o_d_prev[2 * VOCAB + v]);
  o_tok_prev[v] = expf(s + C);
  if (blockIdx.x == 0 && tid == 0) {
    float H = lgS - B / A;
    o_h_prev[0] = H;
    o_f_prev[0] = H - slot[16];
  }
}

// ---------------- host launcher ----------------
extern "C" void kernel_launch(void* const* d_in, const int* in_sizes, int n_in,
                              void* d_out, int out_size, void* d_ws, size_t ws_size,
                              hipStream_t stream) {
  const int*   tokens = (const int*)d_in[0];
  const float* E      = (const float*)d_in[1];
  const float* Ws     = (const float*)d_in[2];
  const float* temp_p = (const float*)d_in[3];
  const float* base_p = (const float*)d_in[4];
  const float* sens_p = (const float*)d_in[5];

  float* out   = (float*)d_out;
  float* o_tok = out;                             // [4][32768]
  float* o_rho = o_tok + SEQ * VOCAB;             // [4][512][512]
  float* o_w   = o_rho + (size_t)SEQ * DD * DD;   // [4][3]
  float* o_sr  = o_w + SEQ * NF;                  // [4]
  float* o_h   = o_sr + SEQ;                      // [4]
  float* o_f   = o_h + SEQ;                       // [4]
  float* o_d   = o_f + SEQ;                       // [4][3][32768]

  float* ws = (float*)d_ws;

  k_init<<<18, 256, 0, stream>>>(ws);

  for (int t = 0; t < SEQ; t++) {
    const float* odp = (t > 0) ? (o_d + (size_t)(t - 1) * NF * VOCAB) : o_d;
    float* otp = (t > 0) ? (o_tok + (size_t)(t - 1) * VOCAB) : o_tok;
    float* ohp = (t > 0) ? (o_h + (t - 1)) : o_h;
    float* ofp = (t > 0) ? (o_f + (t - 1)) : o_f;
    kA<<<(t > 0) ? 200 : 72, 256, 0, stream>>>(tokens, E, Ws, base_p, sens_p,
                                               ws, odp, otp, ohp, ofp, t);
    kB<<<2048, 256, 0, stream>>>((const float4*)E, ws);
    kS<<<1, 256, 0, stream>>>(ws, temp_p, o_w + t * NF, o_sr + t, t);
    kC<<<640, 256, 0, stream>>>(ws, o_rho + (size_t)t * DD * DD,
                                o_d + (size_t)t * NF * VOCAB, t);
  }
  k_tok<<<128, 256, 0, stream>>>(ws, o_d + (size_t)3 * NF * VOCAB,
                                 o_tok + (size_t)3 * VOCAB, o_h + 3, o_f + 3, 3);
}